// Round 2
// baseline (151.340 us; speedup 1.0000x reference)
//
#include <hip/hip_runtime.h>

typedef unsigned short u16;
typedef unsigned int u32;
typedef __attribute__((ext_vector_type(8))) short short8;
typedef __attribute__((ext_vector_type(4))) float f32x4;

__device__ __forceinline__ u16 f2b(float f) {
  u32 u = __builtin_bit_cast(u32, f);
  u32 r = (u + 0x7FFFu + ((u >> 16) & 1u)) >> 16;  // RNE f32->bf16
  return (u16)r;
}

__device__ __forceinline__ void gl_lds16(const void* g, void* l) {
  __builtin_amdgcn_global_load_lds(
      (const __attribute__((address_space(1))) u32*)g,
      (__attribute__((address_space(3))) u32*)l, 16, 0, 0);
}

struct Ptrs8 { const float* p[8]; };

// ---------------------------------------------------------------------------
// Pack/transpose+convert: Wt[g*1024 + n][h*1024 + k] = bf16(W[h*4+g][k][n])
// W matrices are f32 [1024 k][1024 n] (n-contiguous); Wt rows k-contiguous.
// 64x64 f32 LDS tile staged via global_load_lds (lane-linear dest).
// ---------------------------------------------------------------------------
__global__ __launch_bounds__(256) void wt_pack(Ptrs8 w, u16* __restrict__ Wt) {
  __shared__ float lds[64 * 64];     // 16 KB
  const int tid = threadIdx.x;
  const int bid = blockIdx.x;
  const int mat = bid >> 8;            // 0..7
  const int g = mat & 3, h = mat >> 2; // gate, input/hidden half
  const int tile = bid & 255;
  const int kt = tile >> 4, nt = tile & 15;
  const float* __restrict__ src = w.p[mat];

#pragma unroll
  for (int i = 0; i < 4; ++i) {        // 1024 chunks of 4 floats
    int c = tid + i * 256;
    int k = c >> 4, n4 = (c & 15) * 4;
    gl_lds16(src + (size_t)(kt * 64 + k) * 1024 + nt * 64 + n4, &lds[c * 4]);
  }
  asm volatile("s_waitcnt vmcnt(0)");
  __syncthreads();

#pragma unroll
  for (int i = 0; i < 2; ++i) {        // 512 chunks of 8 k-values
    int c = tid + i * 256;
    int n = c & 63, kb = (c >> 6) * 8;
    short8 v;
#pragma unroll
    for (int j = 0; j < 8; ++j) v[j] = (short)f2b(lds[(kb + j) * 64 + n]);
    size_t off = (size_t)(g * 1024 + nt * 64 + n) * 2048 + h * 1024 + kt * 64 + kb;
    *reinterpret_cast<short8*>(Wt + off) = v;
  }
}

// Ap[m][k] (bf16, [4096][2048]) = bf16( k<1024 ? x[m][k] : h0[m][k-1024] )
__global__ __launch_bounds__(256) void xh_pack(const float* __restrict__ x,
                                               const float* __restrict__ h0,
                                               u16* __restrict__ Ap) {
  int t = blockIdx.x * 256 + threadIdx.x;  // 1M threads, 8 elems each
  int m = t >> 8, kc = t & 255;
  const float* src = (kc < 128) ? (x + (size_t)m * 1024 + kc * 8)
                                : (h0 + (size_t)m * 1024 + (kc - 128) * 8);
  float4 a = *reinterpret_cast<const float4*>(src);
  float4 b = *reinterpret_cast<const float4*>(src + 4);
  short8 v;
  v[0] = (short)f2b(a.x); v[1] = (short)f2b(a.y);
  v[2] = (short)f2b(a.z); v[3] = (short)f2b(a.w);
  v[4] = (short)f2b(b.x); v[5] = (short)f2b(b.y);
  v[6] = (short)f2b(b.z); v[7] = (short)f2b(b.w);
  *reinterpret_cast<short8*>(Ap + (size_t)m * 2048 + kc * 8) = v;
}

// bias_total[g*1024+n] = b_input[g][n] + b_hidden[g][n]  (f32)
__global__ void bias_pack(Ptrs8 b, float* __restrict__ bias) {
  int i = blockIdx.x * 1024 + threadIdx.x; // grid 4 x 1024
  int g = i >> 10, n = i & 1023;
  bias[i] = b.p[g][n] + b.p[4 + g][n];
}

// ---------------------------------------------------------------------------
// Fused LSTM GEMM: block tile 128m x 32n x 4 gates, BK=32, 4 waves.
// Wave w owns rows [w*32, w*32+32); acc[g][mr][nr].
// ---------------------------------------------------------------------------
__global__ __launch_bounds__(256) void lstm_fused(
    const u16* __restrict__ Ap, const float* __restrict__ c0,
    const u16* __restrict__ Wt, const float* __restrict__ bias,
    float* __restrict__ out) {
  __shared__ u16 As[2][128 * 32];   // [m][k]
  __shared__ u16 Bs[2][128 * 32];   // [(g*32+n)][k]

  const int tid = threadIdx.x;
  const int lane = tid & 63;
  const int wid = tid >> 6;

  const int bid0 = blockIdx.x;
  const int bid = (bid0 & 7) * 128 + (bid0 >> 3);  // XCD swizzle (1024%8==0)
  const int m0 = (bid >> 5) * 128;
  const int n0 = (bid & 31) * 32;

  const int ac[2] = {tid, tid + 256};
  const u16* asrc[2];
  const u16* bsrc[2];
#pragma unroll
  for (int i = 0; i < 2; ++i) {
    const int c = ac[i];
    const int kh = (c & 3) * 8;
    const int m = c >> 2;
    asrc[i] = Ap + (size_t)(m0 + m) * 2048 + kh;
    const int gg = (c >> 2) >> 5, n = (c >> 2) & 31;
    bsrc[i] = Wt + (size_t)(gg * 1024 + n0 + n) * 2048 + kh;
  }

  f32x4 acc[4][2][2] = {};

  const int fl = lane & 15;
  const int fk = (lane >> 4) * 8;

  auto stage = [&](int buf, int t) {
    const int k0 = t * 32;
#pragma unroll
    for (int i = 0; i < 2; ++i) {
      gl_lds16(asrc[i] + k0, &As[buf][ac[i] * 8]);
      gl_lds16(bsrc[i] + k0, &Bs[buf][ac[i] * 8]);
    }
  };

  stage(0, 0);
  asm volatile("s_waitcnt vmcnt(0)");
  __syncthreads();

  for (int t = 0; t < 64; ++t) {
    const int cur = t & 1;
    if (t < 63) stage(cur ^ 1, t + 1);

    const u16* Ab = As[cur];
    const u16* Bb = Bs[cur];
    short8 af[2];
#pragma unroll
    for (int mr = 0; mr < 2; ++mr)
      af[mr] = *reinterpret_cast<const short8*>(&Ab[(wid * 32 + mr * 16 + fl) * 32 + fk]);
    short8 bf[4][2];
#pragma unroll
    for (int g = 0; g < 4; ++g)
#pragma unroll
      for (int nr = 0; nr < 2; ++nr)
        bf[g][nr] = *reinterpret_cast<const short8*>(&Bb[(g * 32 + nr * 16 + fl) * 32 + fk]);

#pragma unroll
    for (int g = 0; g < 4; ++g)
#pragma unroll
      for (int mr = 0; mr < 2; ++mr)
#pragma unroll
        for (int nr = 0; nr < 2; ++nr)
          acc[g][mr][nr] = __builtin_amdgcn_mfma_f32_16x16x32_bf16(
              af[mr], bf[g][nr], acc[g][mr][nr], 0, 0, 0);

    asm volatile("s_waitcnt vmcnt(0)");
    __syncthreads();
  }

  // ---- fused epilogue: bias + gates + cell update ----
  float bv[4][2];
#pragma unroll
  for (int g = 0; g < 4; ++g)
#pragma unroll
    for (int nr = 0; nr < 2; ++nr)
      bv[g][nr] = bias[g * 1024 + n0 + nr * 16 + fl];

#pragma unroll
  for (int mr = 0; mr < 2; ++mr) {
#pragma unroll
    for (int r = 0; r < 4; ++r) {
      const int row = m0 + wid * 32 + mr * 16 + (lane >> 4) * 4 + r;
#pragma unroll
      for (int nr = 0; nr < 2; ++nr) {
        const int col = n0 + nr * 16 + fl;
        const float zi = acc[0][mr][nr][r] + bv[0][nr];
        const float zf = acc[1][mr][nr][r] + bv[1][nr];
        const float zg = acc[2][mr][nr][r] + bv[2][nr];
        const float zo = acc[3][mr][nr][r] + bv[3][nr];
        const float ig = 1.f / (1.f + __expf(-zi));
        const float fg = 1.f / (1.f + __expf(-zf));
        const float gg = 1.f - 2.f / (__expf(2.f * zg) + 1.f);  // tanh
        const float og = 1.f / (1.f + __expf(-zo));
        const float c0v = c0[(size_t)row * 1024 + col];
        const float c1 = fg * c0v + ig * gg;
        const float h1 = og * c1;
        out[(size_t)row * 1024 + col] = h1;
        out[(size_t)4194304 + (size_t)row * 1024 + col] = c1;
      }
    }
  }
}

// ---------------------------------------------------------------------------
extern "C" void kernel_launch(void* const* d_in, const int* in_sizes, int n_in,
                              void* d_out, int out_size, void* d_ws, size_t ws_size,
                              hipStream_t stream) {
  const float* x  = (const float*)d_in[0];
  const float* h0 = (const float*)d_in[1];
  const float* c0 = (const float*)d_in[2];
  Ptrs8 w, b;
  for (int i = 0; i < 4; ++i) {
    w.p[i]     = (const float*)d_in[3 + 2 * i];   // W_ii, W_if, W_ig, W_io
    b.p[i]     = (const float*)d_in[4 + 2 * i];   // b_ii, b_if, b_ig, b_io
    w.p[4 + i] = (const float*)d_in[11 + 2 * i];  // W_hi, W_hf, W_hg, W_ho
    b.p[4 + i] = (const float*)d_in[12 + 2 * i];  // b_hi, b_hf, b_hg, b_ho
  }
  u16* Wt = (u16*)d_ws;                                        // 16 MB
  u16* Ap = (u16*)((char*)d_ws + (size_t)4096 * 2048 * 2);     // 16 MB
  float* bias = (float*)((char*)d_ws + (size_t)2 * 4096 * 2048 * 2);  // 16 KB
  float* out = (float*)d_out;

  wt_pack<<<2048, 256, 0, stream>>>(w, Wt);
  xh_pack<<<4096, 256, 0, stream>>>(x, h0, Ap);
  bias_pack<<<4, 1024, 0, stream>>>(b, bias);
  lstm_fused<<<1024, 256, 0, stream>>>(Ap, c0, Wt, bias, out);
}

// Round 3
// 126.128 us; speedup vs baseline: 1.1999x; 1.1999x over previous
//
#include <hip/hip_runtime.h>

typedef unsigned short u16;
typedef unsigned int u32;
typedef __attribute__((ext_vector_type(8))) short short8;
typedef __attribute__((ext_vector_type(4))) float f32x4;

__device__ __forceinline__ u16 f2b(float f) {
  u32 u = __builtin_bit_cast(u32, f);
  u32 r = (u + 0x7FFFu + ((u >> 16) & 1u)) >> 16;  // RNE f32->bf16
  return (u16)r;
}

__device__ __forceinline__ void gl_lds16(const void* g, void* l) {
  __builtin_amdgcn_global_load_lds(
      (const __attribute__((address_space(1))) u32*)g,
      (__attribute__((address_space(3))) u32*)l, 16, 0, 0);
}

struct Ptrs8 { const float* p[8]; };

// ---------------------------------------------------------------------------
// Pack/transpose+convert: Wt[g*1024 + n][h*1024 + k] = bf16(W[h*4+g][k][n])
// ---------------------------------------------------------------------------
__global__ __launch_bounds__(256) void wt_pack(Ptrs8 w, u16* __restrict__ Wt) {
  __shared__ float lds[64 * 64];     // 16 KB
  const int tid = threadIdx.x;
  const int bid = blockIdx.x;
  const int mat = bid >> 8;            // 0..7
  const int g = mat & 3, h = mat >> 2;
  const int tile = bid & 255;
  const int kt = tile >> 4, nt = tile & 15;
  const float* __restrict__ src = w.p[mat];

#pragma unroll
  for (int i = 0; i < 4; ++i) {
    int c = tid + i * 256;
    int k = c >> 4, n4 = (c & 15) * 4;
    gl_lds16(src + (size_t)(kt * 64 + k) * 1024 + nt * 64 + n4, &lds[c * 4]);
  }
  asm volatile("s_waitcnt vmcnt(0)");
  __syncthreads();

#pragma unroll
  for (int i = 0; i < 2; ++i) {
    int c = tid + i * 256;
    int n = c & 63, kb = (c >> 6) * 8;
    short8 v;
#pragma unroll
    for (int j = 0; j < 8; ++j) v[j] = (short)f2b(lds[(kb + j) * 64 + n]);
    size_t off = (size_t)(g * 1024 + nt * 64 + n) * 2048 + h * 1024 + kt * 64 + kb;
    *reinterpret_cast<short8*>(Wt + off) = v;
  }
}

// Ap[m][k] (bf16, [4096][2048]) = bf16( k<1024 ? x[m][k] : h0[m][k-1024] )
__global__ __launch_bounds__(256) void xh_pack(const float* __restrict__ x,
                                               const float* __restrict__ h0,
                                               u16* __restrict__ Ap) {
  int t = blockIdx.x * 256 + threadIdx.x;
  int m = t >> 8, kc = t & 255;
  const float* src = (kc < 128) ? (x + (size_t)m * 1024 + kc * 8)
                                : (h0 + (size_t)m * 1024 + (kc - 128) * 8);
  float4 a = *reinterpret_cast<const float4*>(src);
  float4 b = *reinterpret_cast<const float4*>(src + 4);
  short8 v;
  v[0] = (short)f2b(a.x); v[1] = (short)f2b(a.y);
  v[2] = (short)f2b(a.z); v[3] = (short)f2b(a.w);
  v[4] = (short)f2b(b.x); v[5] = (short)f2b(b.y);
  v[6] = (short)f2b(b.z); v[7] = (short)f2b(b.w);
  *reinterpret_cast<short8*>(Ap + (size_t)m * 2048 + kc * 8) = v;
}

__global__ void bias_pack(Ptrs8 b, float* __restrict__ bias) {
  int i = blockIdx.x * 1024 + threadIdx.x;
  int g = i >> 10, n = i & 1023;
  bias[i] = b.p[g][n] + b.p[4 + g][n];
}

// ---------------------------------------------------------------------------
// Fused LSTM GEMM: block 256m x (32n x 4 gates), BK=32, 4 waves stacked on M.
// Wave w owns rows [w*64, w*64+64): 32 MFMA / 12 ds_read_b128 per K-step.
// LDS tiles XOR-swizzled (chunk ^= (row>>1)&3) via pre-swizzled global source.
// ---------------------------------------------------------------------------
__global__ __launch_bounds__(256, 2) void lstm_fused(
    const u16* __restrict__ Ap, const float* __restrict__ c0,
    const u16* __restrict__ Wt, const float* __restrict__ bias,
    float* __restrict__ out) {
  __shared__ u16 As[2][256 * 32];   // 16 KB each
  __shared__ u16 Bs[2][128 * 32];   // 8 KB each

  const int tid = threadIdx.x;
  const int lane = tid & 63;
  const int wid = tid >> 6;

  const int bid0 = blockIdx.x;
  const int bid = (bid0 & 7) * 64 + (bid0 >> 3);  // XCD swizzle (512%8==0)
  const int m0 = (bid >> 5) * 256;
  const int n0 = (bid & 31) * 32;

  // ---- staging maps (pre-swizzled global source, lane-linear LDS dest) ----
  // As: 1024 x 16B chunks (4/thread); Bs: 512 (2/thread)
  size_t aoff[4];
  int achunk[4];
#pragma unroll
  for (int i = 0; i < 4; ++i) {
    const int c = tid + i * 256;
    achunk[i] = c;
    const int m = c >> 2, cp = c & 3;
    const int cg = cp ^ ((m >> 1) & 3);          // swizzle
    aoff[i] = (size_t)(m0 + m) * 2048 + cg * 8;
  }
  size_t boff[2];
  int bchunk[2];
#pragma unroll
  for (int i = 0; i < 2; ++i) {
    const int c = tid + i * 256;
    bchunk[i] = c;
    const int rb = c >> 2, cp = c & 3;
    const int cg = cp ^ ((rb >> 1) & 3);
    const int g = rb >> 5, n = rb & 31;
    boff[i] = (size_t)(g * 1024 + n0 + n) * 2048 + cg * 8;
  }

  auto stage = [&](int buf, int t) {
    const int k0 = t * 32;
#pragma unroll
    for (int i = 0; i < 4; ++i)
      gl_lds16(Ap + aoff[i] + k0, &As[buf][achunk[i] * 8]);
#pragma unroll
    for (int i = 0; i < 2; ++i)
      gl_lds16(Wt + boff[i] + k0, &Bs[buf][bchunk[i] * 8]);
  };

  f32x4 acc[4][4][2] = {};   // [gate][mi][nr]

  const int fl = lane & 15;
  const int qs = ((lane >> 4) ^ ((fl >> 1) & 3)) * 8;  // swizzled k-chunk, lane-const
  const int abase = (wid * 64 + fl) * 32 + qs;
  const int bbase = fl * 32 + qs;

  stage(0, 0);
  asm volatile("s_waitcnt vmcnt(0)");
  __syncthreads();

  for (int t = 0; t < 64; ++t) {
    const int cur = t & 1;
    if (t < 63) stage(cur ^ 1, t + 1);

    const u16* Ab = As[cur];
    const u16* Bb = Bs[cur];
    short8 af[4];
#pragma unroll
    for (int mi = 0; mi < 4; ++mi)
      af[mi] = *reinterpret_cast<const short8*>(&Ab[abase + mi * 16 * 32]);

#pragma unroll
    for (int g = 0; g < 4; ++g) {
      short8 bf0 = *reinterpret_cast<const short8*>(&Bb[bbase + (g * 32) * 32]);
      short8 bf1 = *reinterpret_cast<const short8*>(&Bb[bbase + (g * 32 + 16) * 32]);
#pragma unroll
      for (int mi = 0; mi < 4; ++mi) {
        acc[g][mi][0] = __builtin_amdgcn_mfma_f32_16x16x32_bf16(af[mi], bf0, acc[g][mi][0], 0, 0, 0);
        acc[g][mi][1] = __builtin_amdgcn_mfma_f32_16x16x32_bf16(af[mi], bf1, acc[g][mi][1], 0, 0, 0);
      }
    }

    asm volatile("s_waitcnt vmcnt(0)");
    __syncthreads();
  }

  // ---- fused epilogue ----
  float bv[4][2];
#pragma unroll
  for (int g = 0; g < 4; ++g)
#pragma unroll
    for (int nr = 0; nr < 2; ++nr)
      bv[g][nr] = bias[g * 1024 + n0 + nr * 16 + fl];

#pragma unroll
  for (int mi = 0; mi < 4; ++mi) {
#pragma unroll
    for (int r = 0; r < 4; ++r) {
      const int row = m0 + wid * 64 + mi * 16 + (lane >> 4) * 4 + r;
#pragma unroll
      for (int nr = 0; nr < 2; ++nr) {
        const int col = n0 + nr * 16 + fl;
        const float zi = acc[0][mi][nr][r] + bv[0][nr];
        const float zf = acc[1][mi][nr][r] + bv[1][nr];
        const float zg = acc[2][mi][nr][r] + bv[2][nr];
        const float zo = acc[3][mi][nr][r] + bv[3][nr];
        const float ig = 1.f / (1.f + __expf(-zi));
        const float fg = 1.f / (1.f + __expf(-zf));
        const float gg = 1.f - 2.f / (__expf(2.f * zg) + 1.f);  // tanh
        const float og = 1.f / (1.f + __expf(-zo));
        const float c0v = c0[(size_t)row * 1024 + col];
        const float c1 = fg * c0v + ig * gg;
        const float h1 = og * c1;
        out[(size_t)row * 1024 + col] = h1;
        out[(size_t)4194304 + (size_t)row * 1024 + col] = c1;
      }
    }
  }
}

// ---------------------------------------------------------------------------
extern "C" void kernel_launch(void* const* d_in, const int* in_sizes, int n_in,
                              void* d_out, int out_size, void* d_ws, size_t ws_size,
                              hipStream_t stream) {
  const float* x  = (const float*)d_in[0];
  const float* h0 = (const float*)d_in[1];
  const float* c0 = (const float*)d_in[2];
  Ptrs8 w, b;
  for (int i = 0; i < 4; ++i) {
    w.p[i]     = (const float*)d_in[3 + 2 * i];
    b.p[i]     = (const float*)d_in[4 + 2 * i];
    w.p[4 + i] = (const float*)d_in[11 + 2 * i];
    b.p[4 + i] = (const float*)d_in[12 + 2 * i];
  }
  u16* Wt = (u16*)d_ws;                                        // 16 MB
  u16* Ap = (u16*)((char*)d_ws + (size_t)4096 * 2048 * 2);     // 16 MB
  float* bias = (float*)((char*)d_ws + (size_t)2 * 4096 * 2048 * 2);  // 16 KB
  float* out = (float*)d_out;

  wt_pack<<<2048, 256, 0, stream>>>(w, Wt);
  xh_pack<<<4096, 256, 0, stream>>>(x, h0, Ap);
  bias_pack<<<4, 1024, 0, stream>>>(b, bias);
  lstm_fused<<<512, 256, 0, stream>>>(Ap, c0, Wt, bias, out);
}

// Round 4
// 120.653 us; speedup vs baseline: 1.2543x; 1.0454x over previous
//
#include <hip/hip_runtime.h>

typedef unsigned short u16;
typedef unsigned int u32;
typedef __attribute__((ext_vector_type(8))) short short8;
typedef __attribute__((ext_vector_type(4))) float f32x4;

__device__ __forceinline__ u16 f2b(float f) {
  u32 u = __builtin_bit_cast(u32, f);
  u32 r = (u + 0x7FFFu + ((u >> 16) & 1u)) >> 16;  // RNE f32->bf16
  return (u16)r;
}

__device__ __forceinline__ void gl_lds16(const void* g, void* l) {
  __builtin_amdgcn_global_load_lds(
      (const __attribute__((address_space(1))) u32*)g,
      (__attribute__((address_space(3))) u32*)l, 16, 0, 0);
}

struct Ptrs8 { const float* p[8]; };

// ---------------------------------------------------------------------------
// Pack/transpose+convert: Wt[g*1024 + n][h*1024 + k] = bf16(W[h*4+g][k][n])
// ---------------------------------------------------------------------------
__global__ __launch_bounds__(256) void wt_pack(Ptrs8 w, u16* __restrict__ Wt) {
  __shared__ float lds[64 * 64];     // 16 KB
  const int tid = threadIdx.x;
  const int bid = blockIdx.x;
  const int mat = bid >> 8;            // 0..7
  const int g = mat & 3, h = mat >> 2;
  const int tile = bid & 255;
  const int kt = tile >> 4, nt = tile & 15;
  const float* __restrict__ src = w.p[mat];

#pragma unroll
  for (int i = 0; i < 4; ++i) {
    int c = tid + i * 256;
    int k = c >> 4, n4 = (c & 15) * 4;
    gl_lds16(src + (size_t)(kt * 64 + k) * 1024 + nt * 64 + n4, &lds[c * 4]);
  }
  asm volatile("s_waitcnt vmcnt(0)");
  __syncthreads();

#pragma unroll
  for (int i = 0; i < 2; ++i) {
    int c = tid + i * 256;
    int n = c & 63, kb = (c >> 6) * 8;
    short8 v;
#pragma unroll
    for (int j = 0; j < 8; ++j) v[j] = (short)f2b(lds[(kb + j) * 64 + n]);
    size_t off = (size_t)(g * 1024 + nt * 64 + n) * 2048 + h * 1024 + kt * 64 + kb;
    *reinterpret_cast<short8*>(Wt + off) = v;
  }
}

// Ap[m][k] (bf16, [4096][2048]) = bf16( k<1024 ? x[m][k] : h0[m][k-1024] )
__global__ __launch_bounds__(256) void xh_pack(const float* __restrict__ x,
                                               const float* __restrict__ h0,
                                               u16* __restrict__ Ap) {
  int t = blockIdx.x * 256 + threadIdx.x;
  int m = t >> 8, kc = t & 255;
  const float* src = (kc < 128) ? (x + (size_t)m * 1024 + kc * 8)
                                : (h0 + (size_t)m * 1024 + (kc - 128) * 8);
  float4 a = *reinterpret_cast<const float4*>(src);
  float4 b = *reinterpret_cast<const float4*>(src + 4);
  short8 v;
  v[0] = (short)f2b(a.x); v[1] = (short)f2b(a.y);
  v[2] = (short)f2b(a.z); v[3] = (short)f2b(a.w);
  v[4] = (short)f2b(b.x); v[5] = (short)f2b(b.y);
  v[6] = (short)f2b(b.z); v[7] = (short)f2b(b.w);
  *reinterpret_cast<short8*>(Ap + (size_t)m * 2048 + kc * 8) = v;
}

__global__ void bias_pack(Ptrs8 b, float* __restrict__ bias) {
  int i = blockIdx.x * 1024 + threadIdx.x;
  int g = i >> 10, n = i & 1023;
  bias[i] = b.p[g][n] + b.p[4 + g][n];
}

// ---------------------------------------------------------------------------
// Fused LSTM GEMM: block 256m x (32n x 4 gates), BK=32, 4 waves stacked on M.
// 3-deep LDS pipeline, counted vmcnt(6) across raw s_barrier (T4): tile t+1's
// loads stay in flight while computing tile t. LDS XOR-swizzled as before.
// ---------------------------------------------------------------------------
__global__ __launch_bounds__(256, 2) void lstm_fused(
    const u16* __restrict__ Ap, const float* __restrict__ c0,
    const u16* __restrict__ Wt, const float* __restrict__ bias,
    float* __restrict__ out) {
  __shared__ u16 As[3][256 * 32];   // 16 KB each
  __shared__ u16 Bs[3][128 * 32];   // 8 KB each

  const int tid = threadIdx.x;
  const int lane = tid & 63;
  const int wid = tid >> 6;

  const int bid0 = blockIdx.x;
  const int bid = (bid0 & 7) * 64 + (bid0 >> 3);  // XCD swizzle (512%8==0)
  const int m0 = (bid >> 5) * 256;
  const int n0 = (bid & 31) * 32;

  // ---- staging maps (pre-swizzled global source, lane-linear LDS dest) ----
  size_t aoff[4];
  int achunk[4];
#pragma unroll
  for (int i = 0; i < 4; ++i) {
    const int c = tid + i * 256;
    achunk[i] = c;
    const int m = c >> 2, cp = c & 3;
    const int cg = cp ^ ((m >> 1) & 3);          // swizzle
    aoff[i] = (size_t)(m0 + m) * 2048 + cg * 8;
  }
  size_t boff[2];
  int bchunk[2];
#pragma unroll
  for (int i = 0; i < 2; ++i) {
    const int c = tid + i * 256;
    bchunk[i] = c;
    const int rb = c >> 2, cp = c & 3;
    const int cg = cp ^ ((rb >> 1) & 3);
    const int g = rb >> 5, n = rb & 31;
    boff[i] = (size_t)(g * 1024 + n0 + n) * 2048 + cg * 8;
  }

  auto stage = [&](int buf, int t) {
    const int k0 = t * 32;
#pragma unroll
    for (int i = 0; i < 4; ++i)
      gl_lds16(Ap + aoff[i] + k0, &As[buf][achunk[i] * 8]);
#pragma unroll
    for (int i = 0; i < 2; ++i)
      gl_lds16(Wt + boff[i] + k0, &Bs[buf][bchunk[i] * 8]);
  };

  f32x4 acc[4][4][2] = {};   // [gate][mi][nr]

  const int fl = lane & 15;
  const int qs = ((lane >> 4) ^ ((fl >> 1) & 3)) * 8;  // swizzled k-chunk
  const int abase = (wid * 64 + fl) * 32 + qs;
  const int bbase = fl * 32 + qs;

  auto compute = [&](int buf) {
    const u16* Ab = As[buf];
    const u16* Bb = Bs[buf];
    short8 af[4];
#pragma unroll
    for (int mi = 0; mi < 4; ++mi)
      af[mi] = *reinterpret_cast<const short8*>(&Ab[abase + mi * 16 * 32]);
#pragma unroll
    for (int g = 0; g < 4; ++g) {
      short8 bf0 = *reinterpret_cast<const short8*>(&Bb[bbase + (g * 32) * 32]);
      short8 bf1 = *reinterpret_cast<const short8*>(&Bb[bbase + (g * 32 + 16) * 32]);
#pragma unroll
      for (int mi = 0; mi < 4; ++mi) {
        acc[g][mi][0] = __builtin_amdgcn_mfma_f32_16x16x32_bf16(af[mi], bf0, acc[g][mi][0], 0, 0, 0);
        acc[g][mi][1] = __builtin_amdgcn_mfma_f32_16x16x32_bf16(af[mi], bf1, acc[g][mi][1], 0, 0, 0);
      }
    }
  };

  // prologue: 2 tiles in flight (12 loads/wave)
  stage(0, 0);
  stage(1, 1);

  for (int t = 0; t < 62; ++t) {
    // tile t done (leave t+1's 6 loads in flight), all waves synced
    asm volatile("s_waitcnt vmcnt(6)" ::: "memory");
    __builtin_amdgcn_s_barrier();
    // barrier retired all reads of buf[(t+2)%3] == buf[(t-1)%3]; refill it
    stage((t + 2) % 3, t + 2);
    compute(t % 3);
  }
  // t = 62: outstanding = {62,63}
  asm volatile("s_waitcnt vmcnt(6)" ::: "memory");
  __builtin_amdgcn_s_barrier();
  compute(62 % 3);
  // t = 63: outstanding = {63}
  asm volatile("s_waitcnt vmcnt(0)" ::: "memory");
  __builtin_amdgcn_s_barrier();
  compute(63 % 3);

  // ---- fused epilogue ----
  float bv[4][2];
#pragma unroll
  for (int g = 0; g < 4; ++g)
#pragma unroll
    for (int nr = 0; nr < 2; ++nr)
      bv[g][nr] = bias[g * 1024 + n0 + nr * 16 + fl];

#pragma unroll
  for (int mi = 0; mi < 4; ++mi) {
#pragma unroll
    for (int r = 0; r < 4; ++r) {
      const int row = m0 + wid * 64 + mi * 16 + (lane >> 4) * 4 + r;
#pragma unroll
      for (int nr = 0; nr < 2; ++nr) {
        const int col = n0 + nr * 16 + fl;
        const float zi = acc[0][mi][nr][r] + bv[0][nr];
        const float zf = acc[1][mi][nr][r] + bv[1][nr];
        const float zg = acc[2][mi][nr][r] + bv[2][nr];
        const float zo = acc[3][mi][nr][r] + bv[3][nr];
        const float ig = 1.f / (1.f + __expf(-zi));
        const float fg = 1.f / (1.f + __expf(-zf));
        const float gg = 1.f - 2.f / (__expf(2.f * zg) + 1.f);  // tanh
        const float og = 1.f / (1.f + __expf(-zo));
        const float c0v = c0[(size_t)row * 1024 + col];
        const float c1 = fg * c0v + ig * gg;
        const float h1 = og * c1;
        out[(size_t)row * 1024 + col] = h1;
        out[(size_t)4194304 + (size_t)row * 1024 + col] = c1;
      }
    }
  }
}

// ---------------------------------------------------------------------------
extern "C" void kernel_launch(void* const* d_in, const int* in_sizes, int n_in,
                              void* d_out, int out_size, void* d_ws, size_t ws_size,
                              hipStream_t stream) {
  const float* x  = (const float*)d_in[0];
  const float* h0 = (const float*)d_in[1];
  const float* c0 = (const float*)d_in[2];
  Ptrs8 w, b;
  for (int i = 0; i < 4; ++i) {
    w.p[i]     = (const float*)d_in[3 + 2 * i];
    b.p[i]     = (const float*)d_in[4 + 2 * i];
    w.p[4 + i] = (const float*)d_in[11 + 2 * i];
    b.p[4 + i] = (const float*)d_in[12 + 2 * i];
  }
  u16* Wt = (u16*)d_ws;                                        // 16 MB
  u16* Ap = (u16*)((char*)d_ws + (size_t)4096 * 2048 * 2);     // 16 MB
  float* bias = (float*)((char*)d_ws + (size_t)2 * 4096 * 2048 * 2);  // 16 KB
  float* out = (float*)d_out;

  wt_pack<<<2048, 256, 0, stream>>>(w, Wt);
  xh_pack<<<4096, 256, 0, stream>>>(x, h0, Ap);
  bias_pack<<<4, 1024, 0, stream>>>(b, bias);
  lstm_fused<<<512, 256, 0, stream>>>(Ap, c0, Wt, bias, out);
}

// Round 5
// 101.711 us; speedup vs baseline: 1.4879x; 1.1862x over previous
//
#include <hip/hip_runtime.h>

typedef unsigned short u16;
typedef unsigned int u32;
typedef __attribute__((ext_vector_type(8))) short short8;
typedef __attribute__((ext_vector_type(4))) float f32x4;

__device__ __forceinline__ u16 f2b(float f) {
  u32 u = __builtin_bit_cast(u32, f);
  u32 r = (u + 0x7FFFu + ((u >> 16) & 1u)) >> 16;  // RNE f32->bf16
  return (u16)r;
}

__device__ __forceinline__ void gl_lds16(const void* g, void* l) {
  __builtin_amdgcn_global_load_lds(
      (const __attribute__((address_space(1))) u32*)g,
      (__attribute__((address_space(3))) u32*)l, 16, 0, 0);
}

struct Ptrs8 { const float* p[8]; };

// ---------------------------------------------------------------------------
// Pack/transpose+convert: Wt[g*1024 + n][h*1024 + k] = bf16(W[h*4+g][k][n])
// ---------------------------------------------------------------------------
__global__ __launch_bounds__(256) void wt_pack(Ptrs8 w, u16* __restrict__ Wt) {
  __shared__ float lds[64 * 64];     // 16 KB
  const int tid = threadIdx.x;
  const int bid = blockIdx.x;
  const int mat = bid >> 8;            // 0..7
  const int g = mat & 3, h = mat >> 2;
  const int tile = bid & 255;
  const int kt = tile >> 4, nt = tile & 15;
  const float* __restrict__ src = w.p[mat];

#pragma unroll
  for (int i = 0; i < 4; ++i) {
    int c = tid + i * 256;
    int k = c >> 4, n4 = (c & 15) * 4;
    gl_lds16(src + (size_t)(kt * 64 + k) * 1024 + nt * 64 + n4, &lds[c * 4]);
  }
  asm volatile("s_waitcnt vmcnt(0)");
  __syncthreads();

#pragma unroll
  for (int i = 0; i < 2; ++i) {
    int c = tid + i * 256;
    int n = c & 63, kb = (c >> 6) * 8;
    short8 v;
#pragma unroll
    for (int j = 0; j < 8; ++j) v[j] = (short)f2b(lds[(kb + j) * 64 + n]);
    size_t off = (size_t)(g * 1024 + nt * 64 + n) * 2048 + h * 1024 + kt * 64 + kb;
    *reinterpret_cast<short8*>(Wt + off) = v;
  }
}

// Ap[m][k] (bf16, [4096][2048]) = bf16( k<1024 ? x[m][k] : h0[m][k-1024] )
__global__ __launch_bounds__(256) void xh_pack(const float* __restrict__ x,
                                               const float* __restrict__ h0,
                                               u16* __restrict__ Ap) {
  int t = blockIdx.x * 256 + threadIdx.x;
  int m = t >> 8, kc = t & 255;
  const float* src = (kc < 128) ? (x + (size_t)m * 1024 + kc * 8)
                                : (h0 + (size_t)m * 1024 + (kc - 128) * 8);
  float4 a = *reinterpret_cast<const float4*>(src);
  float4 b = *reinterpret_cast<const float4*>(src + 4);
  short8 v;
  v[0] = (short)f2b(a.x); v[1] = (short)f2b(a.y);
  v[2] = (short)f2b(a.z); v[3] = (short)f2b(a.w);
  v[4] = (short)f2b(b.x); v[5] = (short)f2b(b.y);
  v[6] = (short)f2b(b.z); v[7] = (short)f2b(b.w);
  *reinterpret_cast<short8*>(Ap + (size_t)m * 2048 + kc * 8) = v;
}

__global__ void bias_pack(Ptrs8 b, float* __restrict__ bias) {
  int i = blockIdx.x * 1024 + threadIdx.x;
  int g = i >> 10, n = i & 1023;
  bias[i] = b.p[g][n] + b.p[4 + g][n];
}

// ---------------------------------------------------------------------------
// Fused LSTM GEMM, 8-phase-template port:
// 512 thr / 8 waves (2M x 4N), block 256m x (64n x 4 gates), BK=64, 32 iters.
// Wave (wr,wc): tile 128m x 64effn; effn = 4 gates x 16 cols -> acc[8 mi][4 g].
// B rows packed e = wc*64 + g*16 + u so each wave's 4 n-tiles = 4 gates.
// 4 phases/iter: {ds_reads | stage -> barrier -> lgkm(0) -> prio1 -> 16 MFMA
// -> prio0 -> barrier}; ONE counted vmcnt(4) per iter. 3-bit XOR chunk swizzle.
// ---------------------------------------------------------------------------
#define LD8(base, off) (*reinterpret_cast<const short8*>((base) + (off)))

__global__ __launch_bounds__(512, 2) void lstm_fused(
    const u16* __restrict__ Ap, const float* __restrict__ c0,
    const u16* __restrict__ Wt, const float* __restrict__ bias,
    float* __restrict__ out) {
  __shared__ u16 As[2][256 * 64];   // 32 KB each
  __shared__ u16 Bs[2][256 * 64];   // 32 KB each

  const int tid = threadIdx.x;
  const int lane = tid & 63;
  const int wid = tid >> 6;
  const int wr = wid >> 2;          // M half
  const int wc = wid & 3;           // n-16 block
  const int fl = lane & 15;
  const int hi = lane >> 4;
  const int lo7 = fl & 7;

  const int bid0 = blockIdx.x;
  const int sbid = (bid0 & 7) * 32 + (bid0 >> 3);  // XCD swizzle (256%8==0)
  const int m0 = (sbid >> 4) * 256;
  const int n0 = (sbid & 15) * 64;

  // ---- stage maps: 2048 16B-chunks per tile, 4/thread, linear LDS dest,
  //      global source pre-swizzled: chunk cg = cL ^ (row & 7) ----
  int aoff[4], boff[4];
#pragma unroll
  for (int i = 0; i < 4; ++i) {
    const int L = tid + i * 512;
    const int r = L >> 3, cL = L & 7;
    const int cg = cL ^ (r & 7);
    aoff[i] = (m0 + r) * 2048 + cg * 8;
    const int wce = r >> 6, ge = (r >> 4) & 3, ue = r & 15;
    boff[i] = (ge * 1024 + n0 + wce * 16 + ue) * 2048 + cg * 8;
  }

  auto stageA = [&](int buf, int t) {
    const int k0 = t * 64;
#pragma unroll
    for (int i = 0; i < 4; ++i)
      gl_lds16(Ap + aoff[i] + k0, &As[buf][(tid + i * 512) * 8]);
  };
  auto stageB = [&](int buf, int t) {
    const int k0 = t * 64;
#pragma unroll
    for (int i = 0; i < 4; ++i)
      gl_lds16(Wt + boff[i] + k0, &Bs[buf][(tid + i * 512) * 8]);
  };

  // ---- fragment read bases (element offsets; lane-constant swizzle) ----
  const int c0k = (hi ^ lo7) * 8;          // ks=0 swizzled chunk
  const int c1k = ((4 + hi) ^ lo7) * 8;    // ks=1
  const int arow = (wr * 128 + fl) * 64;
  const int brow = (wc * 64 + fl) * 64;

  f32x4 acc[8][4] = {};   // [mi][gate]

  stageA(0, 0);
  stageB(0, 0);

#define PH_A_MFMA(MI0)                                                        \
  do {                                                                        \
    short8 a00 = LD8(Ab, arow + (MI0) * 1024 + c0k);                          \
    short8 a01 = LD8(Ab, arow + (MI0) * 1024 + c1k);                          \
    short8 a10 = LD8(Ab, arow + (MI0 + 1) * 1024 + c0k);                      \
    short8 a11 = LD8(Ab, arow + (MI0 + 1) * 1024 + c1k);                      \
    __builtin_amdgcn_s_barrier();                                             \
    asm volatile("s_waitcnt lgkmcnt(0)" ::: "memory");                        \
    __builtin_amdgcn_s_setprio(1);                                            \
    _Pragma("unroll")                                                         \
    for (int g = 0; g < 4; ++g) {                                             \
      acc[MI0][g] = __builtin_amdgcn_mfma_f32_16x16x32_bf16(                  \
          a00, bf[g][0], acc[MI0][g], 0, 0, 0);                               \
      acc[MI0][g] = __builtin_amdgcn_mfma_f32_16x16x32_bf16(                  \
          a01, bf[g][1], acc[MI0][g], 0, 0, 0);                               \
      acc[MI0 + 1][g] = __builtin_amdgcn_mfma_f32_16x16x32_bf16(              \
          a10, bf[g][0], acc[MI0 + 1][g], 0, 0, 0);                           \
      acc[MI0 + 1][g] = __builtin_amdgcn_mfma_f32_16x16x32_bf16(              \
          a11, bf[g][1], acc[MI0 + 1][g], 0, 0, 0);                           \
    }                                                                         \
    __builtin_amdgcn_s_setprio(0);                                            \
    __builtin_amdgcn_s_barrier();                                             \
  } while (0)

  for (int t = 0; t < 32; ++t) {
    const int cur = t & 1;
    const u16* Ab = &As[cur][0];
    const u16* Bb = &Bs[cur][0];

    // iter top: issue next A-stage, counted drain of tile t's loads, align
    if (t < 31) {
      stageA(cur ^ 1, t + 1);
      asm volatile("s_waitcnt vmcnt(4)" ::: "memory");
    } else {
      asm volatile("s_waitcnt vmcnt(0)" ::: "memory");
    }
    __builtin_amdgcn_s_barrier();

    // phase 0: all B frags (live across iter) + A mi 0,1
    short8 bf[4][2];
#pragma unroll
    for (int g = 0; g < 4; ++g) {
      bf[g][0] = LD8(Bb, brow + g * 1024 + c0k);
      bf[g][1] = LD8(Bb, brow + g * 1024 + c1k);
    }
    PH_A_MFMA(0);
    if (t < 31) stageB(cur ^ 1, t + 1);
    PH_A_MFMA(2);
    PH_A_MFMA(4);
    PH_A_MFMA(6);
  }

  // ---- fused epilogue: bias + gates + cell update ----
  const int col = n0 + wc * 16 + fl;
  float bv[4];
#pragma unroll
  for (int g = 0; g < 4; ++g) bv[g] = bias[g * 1024 + col];

#pragma unroll
  for (int mi = 0; mi < 8; ++mi) {
#pragma unroll
    for (int r = 0; r < 4; ++r) {
      const int row = m0 + wr * 128 + mi * 16 + hi * 4 + r;
      const float zi = acc[mi][0][r] + bv[0];
      const float zf = acc[mi][1][r] + bv[1];
      const float zg = acc[mi][2][r] + bv[2];
      const float zo = acc[mi][3][r] + bv[3];
      const float ig = 1.f / (1.f + __expf(-zi));
      const float fg = 1.f / (1.f + __expf(-zf));
      const float gg = 1.f - 2.f / (__expf(2.f * zg) + 1.f);  // tanh
      const float og = 1.f / (1.f + __expf(-zo));
      const float c0v = c0[(size_t)row * 1024 + col];
      const float c1 = fg * c0v + ig * gg;
      const float h1 = og * c1;
      out[(size_t)row * 1024 + col] = h1;
      out[(size_t)4194304 + (size_t)row * 1024 + col] = c1;
    }
  }
}

// ---------------------------------------------------------------------------
extern "C" void kernel_launch(void* const* d_in, const int* in_sizes, int n_in,
                              void* d_out, int out_size, void* d_ws, size_t ws_size,
                              hipStream_t stream) {
  const float* x  = (const float*)d_in[0];
  const float* h0 = (const float*)d_in[1];
  const float* c0 = (const float*)d_in[2];
  Ptrs8 w, b;
  for (int i = 0; i < 4; ++i) {
    w.p[i]     = (const float*)d_in[3 + 2 * i];
    b.p[i]     = (const float*)d_in[4 + 2 * i];
    w.p[4 + i] = (const float*)d_in[11 + 2 * i];
    b.p[4 + i] = (const float*)d_in[12 + 2 * i];
  }
  u16* Wt = (u16*)d_ws;                                        // 16 MB
  u16* Ap = (u16*)((char*)d_ws + (size_t)4096 * 2048 * 2);     // 16 MB
  float* bias = (float*)((char*)d_ws + (size_t)2 * 4096 * 2048 * 2);  // 16 KB
  float* out = (float*)d_out;

  wt_pack<<<2048, 256, 0, stream>>>(w, Wt);
  xh_pack<<<4096, 256, 0, stream>>>(x, h0, Ap);
  bias_pack<<<4, 1024, 0, stream>>>(b, bias);
  lstm_fused<<<256, 512, 0, stream>>>(Ap, c0, Wt, bias, out);
}